// Round 13
// baseline (64.683 us; speedup 1.0000x reference)
//
#include <hip/hip_runtime.h>
#include <hip/hip_bf16.h>
#include <math.h>

typedef __attribute__((ext_vector_type(8))) short bf16x8;
typedef __attribute__((ext_vector_type(16))) float f32x16;

#define B_ 2
#define L_ 2048
#define S_ 2048
#define H_ 16
#define E_ 64
#define D_ 64
#define EXP2(x) exp2f(x)

// workspace layout: K bf16 images | V^T bf16 images | partials
#define KOFF 0ull
#define VOFF (8ull << 20)
#define POFF (16ull << 20)
#define SLOT_BYTES 18432ull      // 16KB bf16 acc + 2KB (m,l)
#define NSLOTS 1120ull
#define WS_NEED (POFF + NSLOTS * SLOT_BYTES)   // 37.42 MB (<= 37.75 proven, r10)

// global_load_lds: LDS dest = wave-uniform base + lane*16 (lane0's ptr)
#define GLL(gp, lp) __builtin_amdgcn_global_load_lds( \
    (const __attribute__((address_space(1))) unsigned int*)(gp), \
    (__attribute__((address_space(3))) unsigned int*)(lp), 16, 0, 0)

__device__ __forceinline__ unsigned pkbf(float a, float b) {
  __hip_bfloat162 hh = __float22bfloat162_rn(float2{a, b});
  return *(unsigned*)&hh;
}
__device__ __forceinline__ float bf2f(unsigned us) {   // low 16 bits = bf16
  return __uint_as_float(us << 16);
}
// D-frag row for mfma_f32_32x32x16: row = (r&3) + 8*(r>>2) + 4*hi5
__device__ __forceinline__ int crow(int r, int hi5) {
  return (r & 3) + ((r >> 2) << 3) + (hi5 << 2);
}
// KV-chunking schedule: q<3 ->1 chunk, 3<=q<10 ->2, q>=10 ->3 (R<=11)
__device__ __forceinline__ int nchunks(int q) { return (q >= 10) ? 3 : ((q >= 3) ? 2 : 1); }
__device__ __forceinline__ int slotoff(int q, int c) {
  return (q < 3) ? q : (q < 10) ? 3 + (q - 3) * 2 + c : 17 + (q - 10) * 3 + c;
}

// ---------------- pre-pass: bake bf16 swizzled K and V^T tile images --------
__global__ __launch_bounds__(256)
void fa_pre(const float* __restrict__ Kp, const float* __restrict__ Vp,
            char* __restrict__ ws) {
  const int Bx = blockIdx.x;              // 1024 = 32 bh x 32 tiles
  const int bh = Bx & 31, t = Bx >> 5;
  const int b = bh >> 4, h = bh & 15;
  const int kv0 = t * 64;
  const int tid = threadIdx.x;
  char* dk = ws + KOFF + ((size_t)(bh * 32 + t)) * 8192;
  char* dv = ws + VOFF + ((size_t)(bh * 32 + t)) * 8192;
  // K: row = tid>>2 (64 rows), seg = tid&3 (16 e each)
  const int krow = tid >> 2, ksg = tid & 3;
  const int kswz = (krow & 7) << 4;
  const float* gk = Kp + ((size_t)(b * S_ + kv0 + krow) * H_ + h) * E_ + ksg * 16;
  float4 a0 = ((const float4*)gk)[0], a1 = ((const float4*)gk)[1];
  float4 a2 = ((const float4*)gk)[2], a3 = ((const float4*)gk)[3];
  uint4 u0{pkbf(a0.x, a0.y), pkbf(a0.z, a0.w), pkbf(a1.x, a1.y), pkbf(a1.z, a1.w)};
  uint4 u1{pkbf(a2.x, a2.y), pkbf(a2.z, a2.w), pkbf(a3.x, a3.y), pkbf(a3.z, a3.w)};
  *(uint4*)(dk + ((krow * 128 + ksg * 32) ^ kswz)) = u0;
  *(uint4*)(dk + ((krow * 128 + ksg * 32 + 16) ^ kswz)) = u1;
  // V^T: row d = tid&63, kg = tid>>6 (16 kv each), coalesced global reads
  const int vd = tid & 63, kg = tid >> 6;
  const int vswz = (vd & 7) << 4;
  const float* gv = Vp + ((size_t)(b * S_ + kv0 + kg * 16) * H_ + h) * D_ + vd;
  float v[16];
  #pragma unroll
  for (int k = 0; k < 16; ++k) v[k] = gv[(size_t)k * (H_ * D_)];
  uint4 w0{pkbf(v[0], v[1]), pkbf(v[2], v[3]), pkbf(v[4], v[5]), pkbf(v[6], v[7])};
  uint4 w1{pkbf(v[8], v[9]), pkbf(v[10], v[11]), pkbf(v[12], v[13]), pkbf(v[14], v[15])};
  *(uint4*)(dv + ((vd * 128 + kg * 32) ^ vswz)) = w0;
  *(uint4*)(dv + ((vd * 128 + kg * 32 + 16) ^ vswz)) = w1;
}

// ---------------- main: flash loop, gload_lds staging, bf16 partials --------
__global__ __launch_bounds__(256, 4)
void fa_main(const float* __restrict__ Qp, float* __restrict__ Op,
             char* __restrict__ ws) {
  __shared__ uint4 sbuf[2][1024];   // [buf] = K image 8KB | V^T image 8KB

  const int tid  = threadIdx.x;
  const int lane = tid & 63;
  const int sub  = tid >> 6;        // 4 waves = 4 q-subtiles (32 rows)
  const int l31  = lane & 31;
  const int hi5  = lane >> 5;

  // XCD-chunked, heavy-first: Bx -> (bh, j), j=0..34 -> (q, chunk)
  const int Bx  = blockIdx.x;       // 1120
  const int xcd = Bx & 7, i_ = Bx >> 3;
  const int bh  = xcd * 4 + (i_ & 3);
  const int j   = i_ >> 2;
  int q, c;
  if (j < 18)      { q = 15 - j / 3;       c = j % 3; }
  else if (j < 32) { q = 9 - (j - 18) / 2; c = (j - 18) & 1; }
  else             { q = 34 - j;           c = 0; }
  const int b = bh >> 4, h = bh & 15;
  const int tot = 2 * q + 2, nc = nchunks(q);
  const int base = tot / nc, rem = tot - base * nc;
  const int R  = base + (c < rem ? 1 : 0);
  const int t0 = c * base + (c < rem ? c : rem);
  const int q0 = q << 7;
  const int qw = q0 + sub * 32;

  const float cs = 0.125f * 1.44269504088896f;  // 1/sqrt(E) * log2(e)

  // ---- Q fragments (B-operand of swapped QK^T), pre-scaled ----
  bf16x8 qf[4];
  {
    const int qg = qw + l31;
    const float* gq = Qp + ((size_t)(b * L_ + qg) * H_ + h) * E_ + hi5 * 8;
    #pragma unroll
    for (int ec = 0; ec < 4; ++ec) {
      float4 a = *(const float4*)(gq + ec * 16);
      float4 cc = *(const float4*)(gq + ec * 16 + 4);
      uint4 u;
      u.x = pkbf(a.x * cs, a.y * cs);
      u.y = pkbf(a.z * cs, a.w * cs);
      u.z = pkbf(cc.x * cs, cc.y * cs);
      u.w = pkbf(cc.z * cs, cc.w * cs);
      qf[ec] = *(bf16x8*)&u;
    }
  }

  f32x16 acc[2];
  #pragma unroll
  for (int dt = 0; dt < 2; ++dt)
    #pragma unroll
    for (int rr = 0; rr < 16; ++rr) acc[dt][rr] = 0.f;
  float mrun = -INFINITY, lsum = 0.f;

  const char* gK = ws + KOFF + ((size_t)bh * 32) * 8192;
  const char* gV = ws + VOFF + ((size_t)bh * 32) * 8192;

#define STAGE(buf_, t_) do {                                        \
    const char* sk = gK + (size_t)(t_) * 8192 + tid * 16;           \
    const char* sv = gV + (size_t)(t_) * 8192 + tid * 16;           \
    char* lb = (char*)&sbuf[(buf_)][0] + tid * 16;                  \
    GLL(sk, lb); GLL(sk + 4096, lb + 4096);                         \
    GLL(sv, lb + 8192); GLL(sv + 4096, lb + 12288);                 \
  } while (0)

  STAGE(0, t0);
  __syncthreads();

  int cur = 0;
  for (int t = t0; t < t0 + R; ++t, cur ^= 1) {
    if (t + 1 < t0 + R) STAGE(cur ^ 1, t + 1);   // uniform, all lanes active

    const int kv0 = t * 64;
    if (kv0 <= qw + 31) {
      char* lk = (char*)&sbuf[cur][0];
      char* lv = lk + 8192;
      const bool needmask = (kv0 + 63) > qw;

      // swapped QK^T: st[c2] = S^T[kv 32c2..][q]
      f32x16 st[2];
      #pragma unroll
      for (int c2 = 0; c2 < 2; ++c2)
        #pragma unroll
        for (int rr = 0; rr < 16; ++rr) st[c2][rr] = 0.f;
      __builtin_amdgcn_s_setprio(1);
      #pragma unroll
      for (int c2 = 0; c2 < 2; ++c2) {
        const int row = c2 * 32 + l31;
        const int sw = (row & 7) << 4;
        #pragma unroll
        for (int ec = 0; ec < 4; ++ec) {
          bf16x8 kf = *(bf16x8*)(lk + ((row * 128 + ec * 32 + hi5 * 16) ^ sw));
          st[c2] = __builtin_amdgcn_mfma_f32_32x32x16_bf16(kf, qf[ec], st[c2], 0, 0, 0);
        }
      }
      __builtin_amdgcn_s_setprio(0);

      if (needmask) {
        const int qg = qw + l31;
        #pragma unroll
        for (int c2 = 0; c2 < 2; ++c2)
          #pragma unroll
          for (int rr = 0; rr < 16; ++rr)
            if (kv0 + c2 * 32 + crow(rr, hi5) > qg) st[c2][rr] = -1e30f;
      }

      // ---- online softmax: TREE max (depth 5, not 31-serial) ----
      float mx[8];
      #pragma unroll
      for (int i = 0; i < 8; ++i)
        mx[i] = fmaxf(fmaxf(st[0][i], st[0][i + 8]),
                      fmaxf(st[1][i], st[1][i + 8]));
      #pragma unroll
      for (int i = 0; i < 4; ++i) mx[i] = fmaxf(mx[i], mx[i + 4]);
      mx[0] = fmaxf(mx[0], mx[2]);
      mx[1] = fmaxf(mx[1], mx[3]);
      float pm = fmaxf(mx[0], mx[1]);
      pm = fmaxf(pm, __shfl_xor(pm, 32));

      if (__any(pm > mrun + 8.f)) {       // defer-max (THR=8, log2 domain)
        const float mn = fmaxf(mrun, pm);
        const float f = EXP2(mrun - mn);
        mrun = mn;
        lsum *= f;
        #pragma unroll
        for (int rr = 0; rr < 16; ++rr) {
          const float fr = __shfl(f, crow(rr, hi5));
          acc[0][rr] *= fr;
          acc[1][rr] *= fr;
        }
      }
      {
        // exps (independent, pipelined) then TREE sum
        #pragma unroll
        for (int c2 = 0; c2 < 2; ++c2)
          #pragma unroll
          for (int rr = 0; rr < 16; ++rr)
            st[c2][rr] = EXP2(st[c2][rr] - mrun);
        float ss[8];
        #pragma unroll
        for (int i = 0; i < 8; ++i)
          ss[i] = (st[0][i] + st[0][i + 8]) + (st[1][i] + st[1][i + 8]);
        #pragma unroll
        for (int i = 0; i < 4; ++i) ss[i] += ss[i + 4];
        float ps = (ss[0] + ss[2]) + (ss[1] + ss[3]);
        ps += __shfl_xor(ps, 32);
        lsum += ps;
      }

      // P -> PA fragments (pack pairs + lane^32 exchange)
      uint4 pa[4];
      #pragma unroll
      for (int c2 = 0; c2 < 2; ++c2) {
        unsigned Dw[8];
        #pragma unroll
        for (int jj = 0; jj < 8; ++jj)
          Dw[jj] = pkbf(st[c2][2 * jj], st[c2][2 * jj + 1]);
        unsigned y0 = __shfl_xor((int)(hi5 ? Dw[0] : Dw[2]), 32);
        unsigned y1 = __shfl_xor((int)(hi5 ? Dw[1] : Dw[3]), 32);
        unsigned y2 = __shfl_xor((int)(hi5 ? Dw[4] : Dw[6]), 32);
        unsigned y3 = __shfl_xor((int)(hi5 ? Dw[5] : Dw[7]), 32);
        uint4 p0, p1;
        if (hi5) {
          p0 = uint4{y0, y1, Dw[2], Dw[3]};
          p1 = uint4{y2, y3, Dw[6], Dw[7]};
        } else {
          p0 = uint4{Dw[0], Dw[1], y0, y1};
          p1 = uint4{Dw[4], Dw[5], y2, y3};
        }
        pa[2 * c2]     = p0;
        pa[2 * c2 + 1] = p1;
      }

      // PV: acc[dt] += P(32q x 16kv) . V(16kv x 32d)
      __builtin_amdgcn_s_setprio(1);
      #pragma unroll
      for (int s = 0; s < 4; ++s) {
        #pragma unroll
        for (int dt = 0; dt < 2; ++dt) {
          const int row = dt * 32 + l31;
          bf16x8 vf = *(bf16x8*)(lv + ((row * 128 + s * 32 + hi5 * 16) ^ ((row & 7) << 4)));
          acc[dt] = __builtin_amdgcn_mfma_f32_32x32x16_bf16(*(bf16x8*)&pa[s], vf, acc[dt], 0, 0, 0);
        }
      }
      __builtin_amdgcn_s_setprio(0);
    }
    __syncthreads();
  }

  if (nc == 1) {
    // ---- direct epilogue (q<3): O[q][d] = acc / lsum ----
    const float inv = 1.f / lsum;
    #pragma unroll
    for (int rr = 0; rr < 16; ++rr) {
      const int cr = crow(rr, hi5);
      const float wv = __shfl(inv, cr);
      const int qg = qw + cr;
      float* go = Op + ((size_t)(b * L_ + qg) * H_ + h) * D_ + l31;
      go[0]  = acc[0][rr] * wv;
      go[32] = acc[1][rr] * wv;
    }
    return;
  }

  // ---- write bf16 partial + (m,l); merge kernel combines (no fences) ----
  char* slot = ws + POFF + ((size_t)(bh * 35 + slotoff(q, c))) * SLOT_BYTES;
  uint4* pw = (uint4*)(slot + (size_t)(sub * 64 + lane) * 64);
  #pragma unroll
  for (int dt = 0; dt < 2; ++dt) {
    uint4 A{pkbf(acc[dt][0], acc[dt][1]),  pkbf(acc[dt][2], acc[dt][3]),
            pkbf(acc[dt][4], acc[dt][5]),  pkbf(acc[dt][6], acc[dt][7])};
    uint4 Bq{pkbf(acc[dt][8], acc[dt][9]),  pkbf(acc[dt][10], acc[dt][11]),
             pkbf(acc[dt][12], acc[dt][13]), pkbf(acc[dt][14], acc[dt][15])};
    pw[dt * 2]     = A;
    pw[dt * 2 + 1] = Bq;
  }
  ((float2*)(slot + 16384))[sub * 64 + lane] = float2{mrun, lsum};
#undef STAGE
}

// ---------------- merge: LSE-combine 2..3 partials per (bh,q>=3) -> O -------
__device__ __forceinline__ void unpk(uint4 a, uint4 b, float* o) {
  const unsigned* pa = (const unsigned*)&a;
  const unsigned* pb = (const unsigned*)&b;
  #pragma unroll
  for (int i = 0; i < 4; ++i) {
    o[2 * i]     = bf2f(pa[i] & 0xffffu);
    o[2 * i + 1] = bf2f(pa[i] >> 16);
    o[8 + 2 * i]     = bf2f(pb[i] & 0xffffu);
    o[8 + 2 * i + 1] = bf2f(pb[i] >> 16);
  }
}

__global__ __launch_bounds__(256)
void fa_merge(float* __restrict__ Op, const char* __restrict__ ws) {
  const int Bx = blockIdx.x;        // 416 = 32 bh x 13 q (q=3..15)
  const int bh = Bx / 13, q = 3 + (Bx % 13);
  const int b = bh >> 4, h = bh & 15;
  const int tid = threadIdx.x, lane = tid & 63, sub = tid >> 6;
  const int l31 = lane & 31, hi5 = lane >> 5;
  const int nc = nchunks(q);
  const char* sbase = ws + POFF;

  float A0[16], A1[16], M, Lw;
  {
    const char* s0 = sbase + ((size_t)(bh * 35 + slotoff(q, 0))) * SLOT_BYTES;
    const uint4* pr = (const uint4*)(s0 + (size_t)(sub * 64 + lane) * 64);
    unpk(pr[0], pr[1], A0);
    unpk(pr[2], pr[3], A1);
    float2 ml = ((const float2*)(s0 + 16384))[sub * 64 + lane];
    M = ml.x; Lw = ml.y;
  }
  for (int ci = 1; ci < nc; ++ci) {
    const char* si = sbase + ((size_t)(bh * 35 + slotoff(q, ci))) * SLOT_BYTES;
    const uint4* pr = (const uint4*)(si + (size_t)(sub * 64 + lane) * 64);
    float a0[16], a1[16];
    unpk(pr[0], pr[1], a0);
    unpk(pr[2], pr[3], a1);
    float2 ml = ((const float2*)(si + 16384))[sub * 64 + lane];
    const float mm = fmaxf(M, ml.x);
    const float fA = EXP2(M - mm);
    const float fI = EXP2(ml.x - mm);    // exp2(-inf)=0 covers empty partial
    Lw = Lw * fA + ml.y * fI;
    M = mm;
    #pragma unroll
    for (int rr = 0; rr < 16; ++rr) {
      const int cr = crow(rr, hi5);
      const float fAb = __shfl(fA, cr);
      const float fIb = __shfl(fI, cr);
      A0[rr] = A0[rr] * fAb + a0[rr] * fIb;
      A1[rr] = A1[rr] * fAb + a1[rr] * fIb;
    }
  }
  const float inv = 1.f / Lw;
  #pragma unroll
  for (int rr = 0; rr < 16; ++rr) {
    const int cr = crow(rr, hi5);
    const float wv = __shfl(inv, cr);
    const int qg = (q << 7) + sub * 32 + cr;
    float* go = Op + ((size_t)(b * L_ + qg) * H_ + h) * D_ + l31;
    go[0]  = A0[rr] * wv;
    go[32] = A1[rr] * wv;
  }
}

extern "C" void kernel_launch(void* const* d_in, const int* in_sizes, int n_in,
                              void* d_out, int out_size, void* d_ws, size_t ws_size,
                              hipStream_t stream) {
  (void)in_sizes; (void)n_in; (void)out_size; (void)ws_size;
  const float* Q = (const float*)d_in[0];
  const float* K = (const float*)d_in[1];
  const float* V = (const float*)d_in[2];
  float* O = (float*)d_out;
  char* ws = (char*)d_ws;   // ws_size >= 37.75MB proven (r10); WS_NEED = 37.42MB
  fa_pre<<<dim3(1024), dim3(256), 0, stream>>>(K, V, ws);
  fa_main<<<dim3(1120), dim3(256), 0, stream>>>(Q, O, ws);
  fa_merge<<<dim3(416), dim3(256), 0, stream>>>(O, ws);
}

// Round 14
// 58.000 us; speedup vs baseline: 1.1152x; 1.1152x over previous
//
#include <hip/hip_runtime.h>
#include <hip/hip_bf16.h>
#include <math.h>

typedef __attribute__((ext_vector_type(8))) short bf16x8;
typedef __attribute__((ext_vector_type(16))) float f32x16;

#define B_ 2
#define L_ 2048
#define S_ 2048
#define H_ 16
#define E_ 64
#define D_ 64

// HW exp2: single v_exp_f32 (default exp2f lowers to multi-inst OCML w/ fixups).
// Domain here: x <= ~0 incl. -1e30/-inf -> 0. ~1 ulp, well within bf16 tolerance.
__device__ __forceinline__ float exp2fast(float x) {
  float r;
  asm("v_exp_f32 %0, %1" : "=v"(r) : "v"(x));
  return r;
}
#define EXP2(x) exp2fast(x)

// workspace layout: K bf16 images | V^T bf16 images | partials
#define KOFF 0ull
#define VOFF (8ull << 20)
#define POFF (16ull << 20)
#define SLOT_BYTES 18432ull      // 16KB bf16 acc + 2KB (m,l)
#define NSLOTS 1120ull
#define WS_NEED (POFF + NSLOTS * SLOT_BYTES)   // 37.42 MB (<= 37.75 proven, r10)

// global_load_lds: LDS dest = wave-uniform base + lane*16 (lane0's ptr)
#define GLL(gp, lp) __builtin_amdgcn_global_load_lds( \
    (const __attribute__((address_space(1))) unsigned int*)(gp), \
    (__attribute__((address_space(3))) unsigned int*)(lp), 16, 0, 0)

__device__ __forceinline__ unsigned pkbf(float a, float b) {
  __hip_bfloat162 hh = __float22bfloat162_rn(float2{a, b});
  return *(unsigned*)&hh;
}
__device__ __forceinline__ float bf2f(unsigned us) {   // low 16 bits = bf16
  return __uint_as_float(us << 16);
}
// D-frag row for mfma_f32_32x32x16: row = (r&3) + 8*(r>>2) + 4*hi5
__device__ __forceinline__ int crow(int r, int hi5) {
  return (r & 3) + ((r >> 2) << 3) + (hi5 << 2);
}
// KV-chunking schedule: q<3 ->1 chunk, 3<=q<10 ->2, q>=10 ->3 (R<=11)
__device__ __forceinline__ int nchunks(int q) { return (q >= 10) ? 3 : ((q >= 3) ? 2 : 1); }
__device__ __forceinline__ int slotoff(int q, int c) {
  return (q < 3) ? q : (q < 10) ? 3 + (q - 3) * 2 + c : 17 + (q - 10) * 3 + c;
}

// ---------------- pre-pass: bake bf16 swizzled K and V^T tile images --------
__global__ __launch_bounds__(256)
void fa_pre(const float* __restrict__ Kp, const float* __restrict__ Vp,
            char* __restrict__ ws) {
  const int Bx = blockIdx.x;              // 1024 = 32 bh x 32 tiles
  const int bh = Bx & 31, t = Bx >> 5;
  const int b = bh >> 4, h = bh & 15;
  const int kv0 = t * 64;
  const int tid = threadIdx.x;
  char* dk = ws + KOFF + ((size_t)(bh * 32 + t)) * 8192;
  char* dv = ws + VOFF + ((size_t)(bh * 32 + t)) * 8192;
  // K: row = tid>>2 (64 rows), seg = tid&3 (16 e each)
  const int krow = tid >> 2, ksg = tid & 3;
  const int kswz = (krow & 7) << 4;
  const float* gk = Kp + ((size_t)(b * S_ + kv0 + krow) * H_ + h) * E_ + ksg * 16;
  float4 a0 = ((const float4*)gk)[0], a1 = ((const float4*)gk)[1];
  float4 a2 = ((const float4*)gk)[2], a3 = ((const float4*)gk)[3];
  uint4 u0{pkbf(a0.x, a0.y), pkbf(a0.z, a0.w), pkbf(a1.x, a1.y), pkbf(a1.z, a1.w)};
  uint4 u1{pkbf(a2.x, a2.y), pkbf(a2.z, a2.w), pkbf(a3.x, a3.y), pkbf(a3.z, a3.w)};
  *(uint4*)(dk + ((krow * 128 + ksg * 32) ^ kswz)) = u0;
  *(uint4*)(dk + ((krow * 128 + ksg * 32 + 16) ^ kswz)) = u1;
  // V^T: row d = tid&63, kg = tid>>6 (16 kv each), coalesced global reads
  const int vd = tid & 63, kg = tid >> 6;
  const int vswz = (vd & 7) << 4;
  const float* gv = Vp + ((size_t)(b * S_ + kv0 + kg * 16) * H_ + h) * D_ + vd;
  float v[16];
  #pragma unroll
  for (int k = 0; k < 16; ++k) v[k] = gv[(size_t)k * (H_ * D_)];
  uint4 w0{pkbf(v[0], v[1]), pkbf(v[2], v[3]), pkbf(v[4], v[5]), pkbf(v[6], v[7])};
  uint4 w1{pkbf(v[8], v[9]), pkbf(v[10], v[11]), pkbf(v[12], v[13]), pkbf(v[14], v[15])};
  *(uint4*)(dv + ((vd * 128 + kg * 32) ^ vswz)) = w0;
  *(uint4*)(dv + ((vd * 128 + kg * 32 + 16) ^ vswz)) = w1;
}

// ---------------- main: flash loop, gload_lds staging, bf16 partials --------
__global__ __launch_bounds__(256, 4)
void fa_main(const float* __restrict__ Qp, float* __restrict__ Op,
             char* __restrict__ ws) {
  __shared__ uint4 sbuf[2][1024];   // [buf] = K image 8KB | V^T image 8KB

  const int tid  = threadIdx.x;
  const int lane = tid & 63;
  const int sub  = tid >> 6;        // 4 waves = 4 q-subtiles (32 rows)
  const int l31  = lane & 31;
  const int hi5  = lane >> 5;

  // XCD-chunked, heavy-first: Bx -> (bh, j), j=0..34 -> (q, chunk)
  const int Bx  = blockIdx.x;       // 1120
  const int xcd = Bx & 7, i_ = Bx >> 3;
  const int bh  = xcd * 4 + (i_ & 3);
  const int j   = i_ >> 2;
  int q, c;
  if (j < 18)      { q = 15 - j / 3;       c = j % 3; }
  else if (j < 32) { q = 9 - (j - 18) / 2; c = (j - 18) & 1; }
  else             { q = 34 - j;           c = 0; }
  const int b = bh >> 4, h = bh & 15;
  const int tot = 2 * q + 2, nc = nchunks(q);
  const int base = tot / nc, rem = tot - base * nc;
  const int R  = base + (c < rem ? 1 : 0);
  const int t0 = c * base + (c < rem ? c : rem);
  const int q0 = q << 7;
  const int qw = q0 + sub * 32;

  const float cs = 0.125f * 1.44269504088896f;  // 1/sqrt(E) * log2(e)

  // ---- Q fragments (B-operand of swapped QK^T), pre-scaled ----
  bf16x8 qf[4];
  {
    const int qg = qw + l31;
    const float* gq = Qp + ((size_t)(b * L_ + qg) * H_ + h) * E_ + hi5 * 8;
    #pragma unroll
    for (int ec = 0; ec < 4; ++ec) {
      float4 a = *(const float4*)(gq + ec * 16);
      float4 cc = *(const float4*)(gq + ec * 16 + 4);
      uint4 u;
      u.x = pkbf(a.x * cs, a.y * cs);
      u.y = pkbf(a.z * cs, a.w * cs);
      u.z = pkbf(cc.x * cs, cc.y * cs);
      u.w = pkbf(cc.z * cs, cc.w * cs);
      qf[ec] = *(bf16x8*)&u;
    }
  }

  f32x16 acc[2];
  #pragma unroll
  for (int dt = 0; dt < 2; ++dt)
    #pragma unroll
    for (int rr = 0; rr < 16; ++rr) acc[dt][rr] = 0.f;
  float mrun = -INFINITY, lsum = 0.f;

  const char* gK = ws + KOFF + ((size_t)bh * 32) * 8192;
  const char* gV = ws + VOFF + ((size_t)bh * 32) * 8192;

#define STAGE(buf_, t_) do {                                        \
    const char* sk = gK + (size_t)(t_) * 8192 + tid * 16;           \
    const char* sv = gV + (size_t)(t_) * 8192 + tid * 16;           \
    char* lb = (char*)&sbuf[(buf_)][0] + tid * 16;                  \
    GLL(sk, lb); GLL(sk + 4096, lb + 4096);                         \
    GLL(sv, lb + 8192); GLL(sv + 4096, lb + 12288);                 \
  } while (0)

  STAGE(0, t0);
  __syncthreads();

  int cur = 0;
  for (int t = t0; t < t0 + R; ++t, cur ^= 1) {
    if (t + 1 < t0 + R) STAGE(cur ^ 1, t + 1);   // uniform, all lanes active

    const int kv0 = t * 64;
    if (kv0 <= qw + 31) {
      char* lk = (char*)&sbuf[cur][0];
      char* lv = lk + 8192;
      const bool needmask = (kv0 + 63) > qw;

      // swapped QK^T: st[c2] = S^T[kv 32c2..][q]
      f32x16 st[2];
      #pragma unroll
      for (int c2 = 0; c2 < 2; ++c2)
        #pragma unroll
        for (int rr = 0; rr < 16; ++rr) st[c2][rr] = 0.f;
      __builtin_amdgcn_s_setprio(1);
      #pragma unroll
      for (int c2 = 0; c2 < 2; ++c2) {
        const int row = c2 * 32 + l31;
        const int sw = (row & 7) << 4;
        #pragma unroll
        for (int ec = 0; ec < 4; ++ec) {
          bf16x8 kf = *(bf16x8*)(lk + ((row * 128 + ec * 32 + hi5 * 16) ^ sw));
          st[c2] = __builtin_amdgcn_mfma_f32_32x32x16_bf16(kf, qf[ec], st[c2], 0, 0, 0);
        }
      }
      __builtin_amdgcn_s_setprio(0);

      if (needmask) {
        const int qg = qw + l31;
        #pragma unroll
        for (int c2 = 0; c2 < 2; ++c2)
          #pragma unroll
          for (int rr = 0; rr < 16; ++rr)
            if (kv0 + c2 * 32 + crow(rr, hi5) > qg) st[c2][rr] = -1e30f;
      }

      // ---- online softmax: tree max ----
      float mx[8];
      #pragma unroll
      for (int i = 0; i < 8; ++i)
        mx[i] = fmaxf(fmaxf(st[0][i], st[0][i + 8]),
                      fmaxf(st[1][i], st[1][i + 8]));
      #pragma unroll
      for (int i = 0; i < 4; ++i) mx[i] = fmaxf(mx[i], mx[i + 4]);
      mx[0] = fmaxf(mx[0], mx[2]);
      mx[1] = fmaxf(mx[1], mx[3]);
      float pm = fmaxf(mx[0], mx[1]);
      pm = fmaxf(pm, __shfl_xor(pm, 32));

      if (__any(pm > mrun + 8.f)) {       // defer-max (THR=8, log2 domain)
        const float mn = fmaxf(mrun, pm);
        const float f = EXP2(mrun - mn);
        mrun = mn;
        lsum *= f;
        #pragma unroll
        for (int rr = 0; rr < 16; ++rr) {
          const float fr = __shfl(f, crow(rr, hi5));
          acc[0][rr] *= fr;
          acc[1][rr] *= fr;
        }
      }
      {
        // exps (single v_exp_f32 each, pipelined) then tree sum
        #pragma unroll
        for (int c2 = 0; c2 < 2; ++c2)
          #pragma unroll
          for (int rr = 0; rr < 16; ++rr)
            st[c2][rr] = EXP2(st[c2][rr] - mrun);
        float ss[8];
        #pragma unroll
        for (int i = 0; i < 8; ++i)
          ss[i] = (st[0][i] + st[0][i + 8]) + (st[1][i] + st[1][i + 8]);
        #pragma unroll
        for (int i = 0; i < 4; ++i) ss[i] += ss[i + 4];
        float ps = (ss[0] + ss[2]) + (ss[1] + ss[3]);
        ps += __shfl_xor(ps, 32);
        lsum += ps;
      }

      // P -> PA fragments (pack pairs + lane^32 exchange)
      uint4 pa[4];
      #pragma unroll
      for (int c2 = 0; c2 < 2; ++c2) {
        unsigned Dw[8];
        #pragma unroll
        for (int jj = 0; jj < 8; ++jj)
          Dw[jj] = pkbf(st[c2][2 * jj], st[c2][2 * jj + 1]);
        unsigned y0 = __shfl_xor((int)(hi5 ? Dw[0] : Dw[2]), 32);
        unsigned y1 = __shfl_xor((int)(hi5 ? Dw[1] : Dw[3]), 32);
        unsigned y2 = __shfl_xor((int)(hi5 ? Dw[4] : Dw[6]), 32);
        unsigned y3 = __shfl_xor((int)(hi5 ? Dw[5] : Dw[7]), 32);
        uint4 p0, p1;
        if (hi5) {
          p0 = uint4{y0, y1, Dw[2], Dw[3]};
          p1 = uint4{y2, y3, Dw[6], Dw[7]};
        } else {
          p0 = uint4{Dw[0], Dw[1], y0, y1};
          p1 = uint4{Dw[4], Dw[5], y2, y3};
        }
        pa[2 * c2]     = p0;
        pa[2 * c2 + 1] = p1;
      }

      // PV: acc[dt] += P(32q x 16kv) . V(16kv x 32d)
      __builtin_amdgcn_s_setprio(1);
      #pragma unroll
      for (int s = 0; s < 4; ++s) {
        #pragma unroll
        for (int dt = 0; dt < 2; ++dt) {
          const int row = dt * 32 + l31;
          bf16x8 vf = *(bf16x8*)(lv + ((row * 128 + s * 32 + hi5 * 16) ^ ((row & 7) << 4)));
          acc[dt] = __builtin_amdgcn_mfma_f32_32x32x16_bf16(*(bf16x8*)&pa[s], vf, acc[dt], 0, 0, 0);
        }
      }
      __builtin_amdgcn_s_setprio(0);
    }
    __syncthreads();
  }

  if (nc == 1) {
    // ---- direct epilogue (q<3): O[q][d] = acc / lsum ----
    const float inv = 1.f / lsum;
    #pragma unroll
    for (int rr = 0; rr < 16; ++rr) {
      const int cr = crow(rr, hi5);
      const float wv = __shfl(inv, cr);
      const int qg = qw + cr;
      float* go = Op + ((size_t)(b * L_ + qg) * H_ + h) * D_ + l31;
      go[0]  = acc[0][rr] * wv;
      go[32] = acc[1][rr] * wv;
    }
    return;
  }

  // ---- write bf16 partial + (m,l); merge kernel combines (no fences) ----
  char* slot = ws + POFF + ((size_t)(bh * 35 + slotoff(q, c))) * SLOT_BYTES;
  uint4* pw = (uint4*)(slot + (size_t)(sub * 64 + lane) * 64);
  #pragma unroll
  for (int dt = 0; dt < 2; ++dt) {
    uint4 A{pkbf(acc[dt][0], acc[dt][1]),  pkbf(acc[dt][2], acc[dt][3]),
            pkbf(acc[dt][4], acc[dt][5]),  pkbf(acc[dt][6], acc[dt][7])};
    uint4 Bq{pkbf(acc[dt][8], acc[dt][9]),  pkbf(acc[dt][10], acc[dt][11]),
             pkbf(acc[dt][12], acc[dt][13]), pkbf(acc[dt][14], acc[dt][15])};
    pw[dt * 2]     = A;
    pw[dt * 2 + 1] = Bq;
  }
  ((float2*)(slot + 16384))[sub * 64 + lane] = float2{mrun, lsum};
#undef STAGE
}

// ---------------- merge: LSE-combine 2..3 partials per (bh,q>=3) -> O -------
__device__ __forceinline__ void unpk(uint4 a, uint4 b, float* o) {
  const unsigned* pa = (const unsigned*)&a;
  const unsigned* pb = (const unsigned*)&b;
  #pragma unroll
  for (int i = 0; i < 4; ++i) {
    o[2 * i]     = bf2f(pa[i] & 0xffffu);
    o[2 * i + 1] = bf2f(pa[i] >> 16);
    o[8 + 2 * i]     = bf2f(pb[i] & 0xffffu);
    o[8 + 2 * i + 1] = bf2f(pb[i] >> 16);
  }
}

__global__ __launch_bounds__(256)
void fa_merge(float* __restrict__ Op, const char* __restrict__ ws) {
  const int Bx = blockIdx.x;        // 416 = 32 bh x 13 q (q=3..15)
  const int bh = Bx / 13, q = 3 + (Bx % 13);
  const int b = bh >> 4, h = bh & 15;
  const int tid = threadIdx.x, lane = tid & 63, sub = tid >> 6;
  const int l31 = lane & 31, hi5 = lane >> 5;
  const int nc = nchunks(q);
  const char* sbase = ws + POFF;

  float A0[16], A1[16], M, Lw;
  {
    const char* s0 = sbase + ((size_t)(bh * 35 + slotoff(q, 0))) * SLOT_BYTES;
    const uint4* pr = (const uint4*)(s0 + (size_t)(sub * 64 + lane) * 64);
    unpk(pr[0], pr[1], A0);
    unpk(pr[2], pr[3], A1);
    float2 ml = ((const float2*)(s0 + 16384))[sub * 64 + lane];
    M = ml.x; Lw = ml.y;
  }
  for (int ci = 1; ci < nc; ++ci) {
    const char* si = sbase + ((size_t)(bh * 35 + slotoff(q, ci))) * SLOT_BYTES;
    const uint4* pr = (const uint4*)(si + (size_t)(sub * 64 + lane) * 64);
    float a0[16], a1[16];
    unpk(pr[0], pr[1], a0);
    unpk(pr[2], pr[3], a1);
    float2 ml = ((const float2*)(si + 16384))[sub * 64 + lane];
    const float mm = fmaxf(M, ml.x);
    const float fA = EXP2(M - mm);
    const float fI = EXP2(ml.x - mm);    // exp2(-inf)=0 covers empty partial
    Lw = Lw * fA + ml.y * fI;
    M = mm;
    #pragma unroll
    for (int rr = 0; rr < 16; ++rr) {
      const int cr = crow(rr, hi5);
      const float fAb = __shfl(fA, cr);
      const float fIb = __shfl(fI, cr);
      A0[rr] = A0[rr] * fAb + a0[rr] * fIb;
      A1[rr] = A1[rr] * fAb + a1[rr] * fIb;
    }
  }
  const float inv = 1.f / Lw;
  #pragma unroll
  for (int rr = 0; rr < 16; ++rr) {
    const int cr = crow(rr, hi5);
    const float wv = __shfl(inv, cr);
    const int qg = (q << 7) + sub * 32 + cr;
    float* go = Op + ((size_t)(b * L_ + qg) * H_ + h) * D_ + l31;
    go[0]  = A0[rr] * wv;
    go[32] = A1[rr] * wv;
  }
}

extern "C" void kernel_launch(void* const* d_in, const int* in_sizes, int n_in,
                              void* d_out, int out_size, void* d_ws, size_t ws_size,
                              hipStream_t stream) {
  (void)in_sizes; (void)n_in; (void)out_size; (void)ws_size;
  const float* Q = (const float*)d_in[0];
  const float* K = (const float*)d_in[1];
  const float* V = (const float*)d_in[2];
  float* O = (float*)d_out;
  char* ws = (char*)d_ws;   // ws_size >= 37.75MB proven (r10); WS_NEED = 37.42MB
  fa_pre<<<dim3(1024), dim3(256), 0, stream>>>(K, V, ws);
  fa_main<<<dim3(1120), dim3(256), 0, stream>>>(Q, O, ws);
  fa_merge<<<dim3(416), dim3(256), 0, stream>>>(O, ws);
}

// Round 15
// 57.356 us; speedup vs baseline: 1.1277x; 1.0112x over previous
//
#include <hip/hip_runtime.h>
#include <hip/hip_bf16.h>
#include <math.h>

typedef __attribute__((ext_vector_type(8))) short bf16x8;
typedef __attribute__((ext_vector_type(16))) float f32x16;

#define B_ 2
#define L_ 2048
#define S_ 2048
#define H_ 16
#define E_ 64
#define D_ 64

// HW exp2: single v_exp_f32 (default exp2f lowers to multi-inst OCML w/ fixups).
__device__ __forceinline__ float exp2fast(float x) {
  float r;
  asm("v_exp_f32 %0, %1" : "=v"(r) : "v"(x));
  return r;
}
#define EXP2(x) exp2fast(x)

// workspace layout: K bf16 images | V^T bf16 images | partials
#define KOFF 0ull
#define VOFF (8ull << 20)
#define POFF (16ull << 20)
#define SLOT_BYTES 18432ull      // 16KB bf16 acc + 2KB (m,l)
#define NSLOTS 1120ull
#define WS_NEED (POFF + NSLOTS * SLOT_BYTES)   // 37.42 MB (<= 37.75 proven, r10)

// global_load_lds: LDS dest = wave-uniform base + lane*16 (lane0's ptr)
#define GLL(gp, lp) __builtin_amdgcn_global_load_lds( \
    (const __attribute__((address_space(1))) unsigned int*)(gp), \
    (__attribute__((address_space(3))) unsigned int*)(lp), 16, 0, 0)

__device__ __forceinline__ unsigned pkbf(float a, float b) {
  __hip_bfloat162 hh = __float22bfloat162_rn(float2{a, b});
  return *(unsigned*)&hh;
}
__device__ __forceinline__ float bf2f(unsigned us) {   // low 16 bits = bf16
  return __uint_as_float(us << 16);
}
// D-frag row for mfma_f32_32x32x16: row = (r&3) + 8*(r>>2) + 4*hi5
__device__ __forceinline__ int crow(int r, int hi5) {
  return (r & 3) + ((r >> 2) << 3) + (hi5 << 2);
}
// KV-chunking schedule: q<3 ->1 chunk, 3<=q<10 ->2, q>=10 ->3 (R<=11)
__device__ __forceinline__ int nchunks(int q) { return (q >= 10) ? 3 : ((q >= 3) ? 2 : 1); }
__device__ __forceinline__ int slotoff(int q, int c) {
  return (q < 3) ? q : (q < 10) ? 3 + (q - 3) * 2 + c : 17 + (q - 10) * 3 + c;
}

// ---------------- pre-pass: bake bf16 swizzled K and V^T tile images --------
__global__ __launch_bounds__(256)
void fa_pre(const float* __restrict__ Kp, const float* __restrict__ Vp,
            char* __restrict__ ws) {
  const int Bx = blockIdx.x;              // 1024 = 32 bh x 32 tiles
  const int bh = Bx & 31, t = Bx >> 5;
  const int b = bh >> 4, h = bh & 15;
  const int kv0 = t * 64;
  const int tid = threadIdx.x;
  char* dk = ws + KOFF + ((size_t)(bh * 32 + t)) * 8192;
  char* dv = ws + VOFF + ((size_t)(bh * 32 + t)) * 8192;
  const int krow = tid >> 2, ksg = tid & 3;
  const int kswz = (krow & 7) << 4;
  const float* gk = Kp + ((size_t)(b * S_ + kv0 + krow) * H_ + h) * E_ + ksg * 16;
  float4 a0 = ((const float4*)gk)[0], a1 = ((const float4*)gk)[1];
  float4 a2 = ((const float4*)gk)[2], a3 = ((const float4*)gk)[3];
  uint4 u0{pkbf(a0.x, a0.y), pkbf(a0.z, a0.w), pkbf(a1.x, a1.y), pkbf(a1.z, a1.w)};
  uint4 u1{pkbf(a2.x, a2.y), pkbf(a2.z, a2.w), pkbf(a3.x, a3.y), pkbf(a3.z, a3.w)};
  *(uint4*)(dk + ((krow * 128 + ksg * 32) ^ kswz)) = u0;
  *(uint4*)(dk + ((krow * 128 + ksg * 32 + 16) ^ kswz)) = u1;
  const int vd = tid & 63, kg = tid >> 6;
  const int vswz = (vd & 7) << 4;
  const float* gv = Vp + ((size_t)(b * S_ + kv0 + kg * 16) * H_ + h) * D_ + vd;
  float v[16];
  #pragma unroll
  for (int k = 0; k < 16; ++k) v[k] = gv[(size_t)k * (H_ * D_)];
  uint4 w0{pkbf(v[0], v[1]), pkbf(v[2], v[3]), pkbf(v[4], v[5]), pkbf(v[6], v[7])};
  uint4 w1{pkbf(v[8], v[9]), pkbf(v[10], v[11]), pkbf(v[12], v[13]), pkbf(v[14], v[15])};
  *(uint4*)(dv + ((vd * 128 + kg * 32) ^ vswz)) = w0;
  *(uint4*)(dv + ((vd * 128 + kg * 32 + 16) ^ vswz)) = w1;
}

// ---------------- main: flash loop, counted-vmcnt pipeline ------------------
__global__ __launch_bounds__(256, 4)
void fa_main(const float* __restrict__ Qp, float* __restrict__ Op,
             char* __restrict__ ws) {
  __shared__ uint4 sbuf[2][1024];   // [buf] = K image 8KB | V^T image 8KB

  const int tid  = threadIdx.x;
  const int lane = tid & 63;
  const int sub  = tid >> 6;        // 4 waves = 4 q-subtiles (32 rows)
  const int l31  = lane & 31;
  const int hi5  = lane >> 5;

  // XCD-chunked, heavy-first: Bx -> (bh, j), j=0..34 -> (q, chunk)
  const int Bx  = blockIdx.x;       // 1120
  const int xcd = Bx & 7, i_ = Bx >> 3;
  const int bh  = xcd * 4 + (i_ & 3);
  const int j   = i_ >> 2;
  int q, c;
  if (j < 18)      { q = 15 - j / 3;       c = j % 3; }
  else if (j < 32) { q = 9 - (j - 18) / 2; c = (j - 18) & 1; }
  else             { q = 34 - j;           c = 0; }
  const int b = bh >> 4, h = bh & 15;
  const int tot = 2 * q + 2, nc = nchunks(q);
  const int base = tot / nc, rem = tot - base * nc;
  const int R  = base + (c < rem ? 1 : 0);
  const int t0 = c * base + (c < rem ? c : rem);
  const int q0 = q << 7;
  const int qw = q0 + sub * 32;

  const float cs = 0.125f * 1.44269504088896f;  // 1/sqrt(E) * log2(e)

  // ---- Q fragments (B-operand of swapped QK^T), pre-scaled ----
  bf16x8 qf[4];
  {
    const int qg = qw + l31;
    const float* gq = Qp + ((size_t)(b * L_ + qg) * H_ + h) * E_ + hi5 * 8;
    #pragma unroll
    for (int ec = 0; ec < 4; ++ec) {
      float4 a = *(const float4*)(gq + ec * 16);
      float4 cc = *(const float4*)(gq + ec * 16 + 4);
      uint4 u;
      u.x = pkbf(a.x * cs, a.y * cs);
      u.y = pkbf(a.z * cs, a.w * cs);
      u.z = pkbf(cc.x * cs, cc.y * cs);
      u.w = pkbf(cc.z * cs, cc.w * cs);
      qf[ec] = *(bf16x8*)&u;
    }
  }

  f32x16 acc[2];
  #pragma unroll
  for (int dt = 0; dt < 2; ++dt)
    #pragma unroll
    for (int rr = 0; rr < 16; ++rr) acc[dt][rr] = 0.f;
  // defer-max with m init 0 (scores bounded by rescale THR=8 -> p <= 256)
  float mrun = 0.f, lsum = 0.f;

  const char* gK = ws + KOFF + ((size_t)bh * 32) * 8192;
  const char* gV = ws + VOFF + ((size_t)bh * 32) * 8192;

#define STAGE(buf_, t_) do {                                        \
    const char* sk = gK + (size_t)(t_) * 8192 + tid * 16;           \
    const char* sv = gV + (size_t)(t_) * 8192 + tid * 16;           \
    char* lb = (char*)&sbuf[(buf_)][0] + tid * 16;                  \
    GLL(sk, lb); GLL(sk + 4096, lb + 4096);                         \
    GLL(sv, lb + 8192); GLL(sv + 4096, lb + 12288);                 \
  } while (0)

  STAGE(0, t0);
  asm volatile("s_waitcnt vmcnt(0)\n\ts_barrier" ::: "memory");

  int cur = 0;
  for (int t = t0; t < t0 + R; ++t, cur ^= 1) {
    const bool have_next = (t + 1) < (t0 + R);
    if (have_next) {
      STAGE(cur ^ 1, t + 1);
      // T4: keep this iter's 4 prefetch GLLs in flight across the barrier;
      // only the PRIOR tile's loads (older than newest 4) must have landed.
      asm volatile("s_waitcnt vmcnt(4)\n\ts_barrier" ::: "memory");
    } else {
      asm volatile("s_waitcnt vmcnt(0)\n\ts_barrier" ::: "memory");
    }

    const int kv0 = t * 64;
    if (kv0 <= qw + 31) {
      char* lk = (char*)&sbuf[cur][0];
      char* lv = lk + 8192;
      const bool needmask = (kv0 + 63) > qw;

      // swapped QK^T with C-init = -mrun  ->  st = S - mrun from the MFMA
      f32x16 st[2];
      const float nm = -mrun;
      #pragma unroll
      for (int c2 = 0; c2 < 2; ++c2)
        #pragma unroll
        for (int rr = 0; rr < 16; ++rr) st[c2][rr] = nm;
      __builtin_amdgcn_s_setprio(1);
      #pragma unroll
      for (int c2 = 0; c2 < 2; ++c2) {
        const int row = c2 * 32 + l31;
        const int sw = (row & 7) << 4;
        #pragma unroll
        for (int ec = 0; ec < 4; ++ec) {
          bf16x8 kf = *(bf16x8*)(lk + ((row * 128 + ec * 32 + hi5 * 16) ^ sw));
          st[c2] = __builtin_amdgcn_mfma_f32_32x32x16_bf16(kf, qf[ec], st[c2], 0, 0, 0);
        }
      }
      __builtin_amdgcn_s_setprio(0);

      if (needmask) {
        const int qg = qw + l31;
        #pragma unroll
        for (int c2 = 0; c2 < 2; ++c2)
          #pragma unroll
          for (int rr = 0; rr < 16; ++rr)
            if (kv0 + c2 * 32 + crow(rr, hi5) > qg) st[c2][rr] = -1e30f;
      }

      // tree max of (S - mrun)
      float mx[8];
      #pragma unroll
      for (int i = 0; i < 8; ++i)
        mx[i] = fmaxf(fmaxf(st[0][i], st[0][i + 8]),
                      fmaxf(st[1][i], st[1][i + 8]));
      #pragma unroll
      for (int i = 0; i < 4; ++i) mx[i] = fmaxf(mx[i], mx[i + 4]);
      mx[0] = fmaxf(mx[0], mx[2]);
      mx[1] = fmaxf(mx[1], mx[3]);
      float pmx = fmaxf(mx[0], mx[1]);
      pmx = fmaxf(pmx, __shfl_xor(pmx, 32));

      if (__any(pmx > 8.f)) {            // rare: rescale (defer-max THR=8)
        pmx = fmaxf(pmx, 0.f);
        const float f = EXP2(-pmx);
        mrun += pmx;
        lsum *= f;
        #pragma unroll
        for (int rr = 0; rr < 16; ++rr) {
          const float fr = __shfl(f, crow(rr, hi5));
          acc[0][rr] *= fr;
          acc[1][rr] *= fr;
        }
        const float npmx = -pmx;
        #pragma unroll
        for (int c2 = 0; c2 < 2; ++c2)
          #pragma unroll
          for (int rr = 0; rr < 16; ++rr) st[c2][rr] += npmx;
      }
      {
        // p = exp2(st) directly (no per-element subtract), then tree sum
        #pragma unroll
        for (int c2 = 0; c2 < 2; ++c2)
          #pragma unroll
          for (int rr = 0; rr < 16; ++rr)
            st[c2][rr] = EXP2(st[c2][rr]);
        float ss[8];
        #pragma unroll
        for (int i = 0; i < 8; ++i)
          ss[i] = (st[0][i] + st[0][i + 8]) + (st[1][i] + st[1][i + 8]);
        #pragma unroll
        for (int i = 0; i < 4; ++i) ss[i] += ss[i + 4];
        float ps = (ss[0] + ss[2]) + (ss[1] + ss[3]);
        ps += __shfl_xor(ps, 32);
        lsum += ps;
      }

      // P -> PA fragments (pack pairs + lane^32 exchange)
      uint4 pa[4];
      #pragma unroll
      for (int c2 = 0; c2 < 2; ++c2) {
        unsigned Dw[8];
        #pragma unroll
        for (int jj = 0; jj < 8; ++jj)
          Dw[jj] = pkbf(st[c2][2 * jj], st[c2][2 * jj + 1]);
        unsigned y0 = __shfl_xor((int)(hi5 ? Dw[0] : Dw[2]), 32);
        unsigned y1 = __shfl_xor((int)(hi5 ? Dw[1] : Dw[3]), 32);
        unsigned y2 = __shfl_xor((int)(hi5 ? Dw[4] : Dw[6]), 32);
        unsigned y3 = __shfl_xor((int)(hi5 ? Dw[5] : Dw[7]), 32);
        uint4 p0, p1;
        if (hi5) {
          p0 = uint4{y0, y1, Dw[2], Dw[3]};
          p1 = uint4{y2, y3, Dw[6], Dw[7]};
        } else {
          p0 = uint4{Dw[0], Dw[1], y0, y1};
          p1 = uint4{Dw[4], Dw[5], y2, y3};
        }
        pa[2 * c2]     = p0;
        pa[2 * c2 + 1] = p1;
      }

      // PV: acc[dt] += P(32q x 16kv) . V(16kv x 32d)
      __builtin_amdgcn_s_setprio(1);
      #pragma unroll
      for (int s = 0; s < 4; ++s) {
        #pragma unroll
        for (int dt = 0; dt < 2; ++dt) {
          const int row = dt * 32 + l31;
          bf16x8 vf = *(bf16x8*)(lv + ((row * 128 + s * 32 + hi5 * 16) ^ ((row & 7) << 4)));
          acc[dt] = __builtin_amdgcn_mfma_f32_32x32x16_bf16(*(bf16x8*)&pa[s], vf, acc[dt], 0, 0, 0);
        }
      }
      __builtin_amdgcn_s_setprio(0);
    }
    // protect buf[cur] from next iteration's STAGE overwrite (no vmcnt drain)
    asm volatile("s_barrier" ::: "memory");
  }

  if (nc == 1) {
    const float inv = 1.f / lsum;
    #pragma unroll
    for (int rr = 0; rr < 16; ++rr) {
      const int cr = crow(rr, hi5);
      const float wv = __shfl(inv, cr);
      const int qg = qw + cr;
      float* go = Op + ((size_t)(b * L_ + qg) * H_ + h) * D_ + l31;
      go[0]  = acc[0][rr] * wv;
      go[32] = acc[1][rr] * wv;
    }
    return;
  }

  // ---- write bf16 partial + (m,l); merge kernel combines (no fences) ----
  char* slot = ws + POFF + ((size_t)(bh * 35 + slotoff(q, c))) * SLOT_BYTES;
  uint4* pw = (uint4*)(slot + (size_t)(sub * 64 + lane) * 64);
  #pragma unroll
  for (int dt = 0; dt < 2; ++dt) {
    uint4 A{pkbf(acc[dt][0], acc[dt][1]),  pkbf(acc[dt][2], acc[dt][3]),
            pkbf(acc[dt][4], acc[dt][5]),  pkbf(acc[dt][6], acc[dt][7])};
    uint4 Bq{pkbf(acc[dt][8], acc[dt][9]),  pkbf(acc[dt][10], acc[dt][11]),
             pkbf(acc[dt][12], acc[dt][13]), pkbf(acc[dt][14], acc[dt][15])};
    pw[dt * 2]     = A;
    pw[dt * 2 + 1] = Bq;
  }
  ((float2*)(slot + 16384))[sub * 64 + lane] = float2{mrun, lsum};
#undef STAGE
}

// ---------------- merge: LSE-combine 2..3 partials per (bh,q>=3) -> O -------
__device__ __forceinline__ void unpk(uint4 a, uint4 b, float* o) {
  const unsigned* pa = (const unsigned*)&a;
  const unsigned* pb = (const unsigned*)&b;
  #pragma unroll
  for (int i = 0; i < 4; ++i) {
    o[2 * i]     = bf2f(pa[i] & 0xffffu);
    o[2 * i + 1] = bf2f(pa[i] >> 16);
    o[8 + 2 * i]     = bf2f(pb[i] & 0xffffu);
    o[8 + 2 * i + 1] = bf2f(pb[i] >> 16);
  }
}

__global__ __launch_bounds__(256)
void fa_merge(float* __restrict__ Op, const char* __restrict__ ws) {
  const int Bx = blockIdx.x;        // 416 = 32 bh x 13 q (q=3..15)
  const int bh = Bx / 13, q = 3 + (Bx % 13);
  const int b = bh >> 4, h = bh & 15;
  const int tid = threadIdx.x, lane = tid & 63, sub = tid >> 6;
  const int l31 = lane & 31, hi5 = lane >> 5;
  const int nc = nchunks(q);
  const char* sbase = ws + POFF;

  float A0[16], A1[16], M, Lw;
  {
    const char* s0 = sbase + ((size_t)(bh * 35 + slotoff(q, 0))) * SLOT_BYTES;
    const uint4* pr = (const uint4*)(s0 + (size_t)(sub * 64 + lane) * 64);
    unpk(pr[0], pr[1], A0);
    unpk(pr[2], pr[3], A1);
    float2 ml = ((const float2*)(s0 + 16384))[sub * 64 + lane];
    M = ml.x; Lw = ml.y;
  }
  for (int ci = 1; ci < nc; ++ci) {
    const char* si = sbase + ((size_t)(bh * 35 + slotoff(q, ci))) * SLOT_BYTES;
    const uint4* pr = (const uint4*)(si + (size_t)(sub * 64 + lane) * 64);
    float a0[16], a1[16];
    unpk(pr[0], pr[1], a0);
    unpk(pr[2], pr[3], a1);
    float2 ml = ((const float2*)(si + 16384))[sub * 64 + lane];
    const float mm = fmaxf(M, ml.x);
    const float fA = EXP2(M - mm);
    const float fI = EXP2(ml.x - mm);
    Lw = Lw * fA + ml.y * fI;
    M = mm;
    #pragma unroll
    for (int rr = 0; rr < 16; ++rr) {
      const int cr = crow(rr, hi5);
      const float fAb = __shfl(fA, cr);
      const float fIb = __shfl(fI, cr);
      A0[rr] = A0[rr] * fAb + a0[rr] * fIb;
      A1[rr] = A1[rr] * fAb + a1[rr] * fIb;
    }
  }
  const float inv = 1.f / Lw;
  #pragma unroll
  for (int rr = 0; rr < 16; ++rr) {
    const int cr = crow(rr, hi5);
    const float wv = __shfl(inv, cr);
    const int qg = (q << 7) + sub * 32 + cr;
    float* go = Op + ((size_t)(b * L_ + qg) * H_ + h) * D_ + l31;
    go[0]  = A0[rr] * wv;
    go[32] = A1[rr] * wv;
  }
}

extern "C" void kernel_launch(void* const* d_in, const int* in_sizes, int n_in,
                              void* d_out, int out_size, void* d_ws, size_t ws_size,
                              hipStream_t stream) {
  (void)in_sizes; (void)n_in; (void)out_size; (void)ws_size;
  const float* Q = (const float*)d_in[0];
  const float* K = (const float*)d_in[1];
  const float* V = (const float*)d_in[2];
  float* O = (float*)d_out;
  char* ws = (char*)d_ws;   // ws_size >= 37.75MB proven (r10); WS_NEED = 37.42MB
  fa_pre<<<dim3(1024), dim3(256), 0, stream>>>(K, V, ws);
  fa_main<<<dim3(1120), dim3(256), 0, stream>>>(Q, O, ws);
  fa_merge<<<dim3(416), dim3(256), 0, stream>>>(O, ws);
}